// Round 1
// baseline (255.362 us; speedup 1.0000x reference)
//
#include <hip/hip_runtime.h>
#include <math.h>

#define BATCH 4096
#define SEQL  512
#define NF    32
#define DEMB  8
#define DOUT  64

// window-table geometry: branches ks=2,3,4,5; window counts 25,125,625,3125
// swin concat offsets: 0,25,150,775 ; total 3900
// hwin (float offset in ws): 4096 + global_window_id*32
#define NWIN_TOTAL 3900
#define HWIN_OFF   4096

__device__ __forceinline__ float gelu_exact(float x) {
    return 0.5f * x * (1.0f + erff(x * 0.70710678118654752f));
}

__global__ __launch_bounds__(256) void precompute_tables(
    const float* __restrict__ emb,
    const float* __restrict__ cw0, const float* __restrict__ cb0,
    const float* __restrict__ aw0, const float* __restrict__ ab0,
    const float* __restrict__ cw1, const float* __restrict__ cb1,
    const float* __restrict__ aw1, const float* __restrict__ ab1,
    const float* __restrict__ cw2, const float* __restrict__ cb2,
    const float* __restrict__ aw2, const float* __restrict__ ab2,
    const float* __restrict__ cw3, const float* __restrict__ cb3,
    const float* __restrict__ aw3, const float* __restrict__ ab3,
    float* __restrict__ ws)
{
    int tid = blockIdx.x * blockDim.x + threadIdx.x;
    if (tid >= NWIN_TOTAL) return;

    int w, ks;
    const float *cw, *cb, *aw, *ab;
    if (tid < 25)       { w = tid;       ks = 2; cw = cw0; cb = cb0; aw = aw0; ab = ab0; }
    else if (tid < 150) { w = tid - 25;  ks = 3; cw = cw1; cb = cb1; aw = aw1; ab = ab1; }
    else if (tid < 775) { w = tid - 150; ks = 4; cw = cw2; cb = cb2; aw = aw2; ab = ab2; }
    else                { w = tid - 775; ks = 5; cw = cw3; cb = cb3; aw = aw3; ab = ab3; }

    float h[NF];
#pragma unroll
    for (int f = 0; f < NF; ++f) h[f] = cb[f];

    // digits little-endian extraction: tap t = ks-1 down to 0 gets w%5 first
    int ww = w;
    for (int t = ks - 1; t >= 0; --t) {
        int d = ww % 5; ww /= 5;
        const float* e = emb + d * DEMB;   // row PAD_IDX is zero in the input
#pragma unroll
        for (int f = 0; f < NF; ++f) {
            float a = 0.0f;
#pragma unroll
            for (int c = 0; c < DEMB; ++c)
                a += e[c] * cw[(f * DEMB + c) * ks + t];
            h[f] += a;
        }
    }

    float s = ab[0];
#pragma unroll
    for (int f = 0; f < NF; ++f) {
        float g = gelu_exact(h[f]);
        h[f] = g;
        s += g * aw[f];
    }

    ws[tid] = s;                     // swin (concatenated across branches)
    float* hrow = ws + HWIN_OFF + tid * NF;
#pragma unroll
    for (int f = 0; f < NF; ++f) hrow[f] = h[f];
}

__global__ __launch_bounds__(256) void fused_main(
    const int*   __restrict__ xidx,
    const float* __restrict__ ws,
    const float* __restrict__ projw, const float* __restrict__ projb,
    const float* __restrict__ gamma, const float* __restrict__ beta,
    float* __restrict__ out)
{
    __shared__ int   xs[SEQL];
    __shared__ float feat[4 * NF];

    const int b   = blockIdx.x;
    const int tid = threadIdx.x;

#pragma unroll
    for (int i = tid; i < SEQL; i += 256) xs[i] = xidx[b * SEQL + i];
    __syncthreads();

    const int wave = tid >> 6;
    const int lane = tid & 63;

    constexpr int KS[4]  = {2, 3, 4, 5};
    constexpr int LP[4]  = {511, 510, 509, 508};
    constexpr int SWB[4] = {0, 25, 150, 775};

    const int ks = KS[wave];
    const int Lp = LP[wave];
    const float* swin = ws + SWB[wave];
    const float* hwin = ws + HWIN_OFF + SWB[wave] * NF;

    // ---- pass 1: window ids + scores, running max ----
    int   wv[8];
    float sv[8];
    float m = -INFINITY;
#pragma unroll
    for (int it = 0; it < 8; ++it) {
        int l = lane + it * 64;
        if (l < Lp) {
            int w = xs[l];
            for (int t = 1; t < ks; ++t) w = w * 5 + xs[l + t];
            float s = swin[w];
            wv[it] = w; sv[it] = s;
            m = fmaxf(m, s);
        } else {
            wv[it] = 0; sv[it] = -INFINITY;
        }
    }
#pragma unroll
    for (int off = 32; off; off >>= 1) m = fmaxf(m, __shfl_xor(m, off));

    float ssum = 0.0f;
#pragma unroll
    for (int it = 0; it < 8; ++it) {
        float e = __expf(sv[it] - m);   // -inf -> 0 for invalid slots
        sv[it] = e;
        ssum += e;
    }
#pragma unroll
    for (int off = 32; off; off >>= 1) ssum += __shfl_xor(ssum, off);
    const float inv = 1.0f / ssum;

    // ---- pass 2: weighted pool over positions ----
    float acc[NF];
#pragma unroll
    for (int j = 0; j < NF; ++j) acc[j] = 0.0f;

#pragma unroll
    for (int it = 0; it < 8; ++it) {
        int l = lane + it * 64;
        if (l < Lp) {
            float p = sv[it];
            const float4* row = (const float4*)(hwin + wv[it] * NF);
#pragma unroll
            for (int q = 0; q < 8; ++q) {
                float4 r = row[q];
                acc[q * 4 + 0] += p * r.x;
                acc[q * 4 + 1] += p * r.y;
                acc[q * 4 + 2] += p * r.z;
                acc[q * 4 + 3] += p * r.w;
            }
        }
    }

#pragma unroll
    for (int off = 32; off; off >>= 1) {
#pragma unroll
        for (int j = 0; j < NF; ++j) acc[j] += __shfl_xor(acc[j], off);
    }

    if (lane == 0) {
#pragma unroll
        for (int j = 0; j < NF; ++j) feat[wave * NF + j] = acc[j] * inv;
    }
    __syncthreads();

    // ---- projection + GELU + LayerNorm (wave 0) ----
    if (tid < DOUT) {
        float z = projb[tid];
        const float4* pw = (const float4*)(projw + tid * (4 * NF));
#pragma unroll
        for (int q = 0; q < 32; ++q) {
            float4 wq = pw[q];
            const float* fj = feat + q * 4;
            z += wq.x * fj[0] + wq.y * fj[1] + wq.z * fj[2] + wq.w * fj[3];
        }
        z = gelu_exact(z);

        float s1 = z, s2 = z * z;
#pragma unroll
        for (int off = 32; off; off >>= 1) {
            s1 += __shfl_xor(s1, off);
            s2 += __shfl_xor(s2, off);
        }
        const float mu  = s1 * (1.0f / 64.0f);
        const float var = s2 * (1.0f / 64.0f) - mu * mu;
        const float r   = rsqrtf(var + 1e-5f);
        out[b * DOUT + tid] = (z - mu) * r * gamma[tid] + beta[tid];
    }
}

extern "C" void kernel_launch(void* const* d_in, const int* in_sizes, int n_in,
                              void* d_out, int out_size, void* d_ws, size_t ws_size,
                              hipStream_t stream) {
    const int*   xidx = (const int*)d_in[0];
    const float* emb  = (const float*)d_in[1];
    const float* cw[4]; const float* cb[4]; const float* aw[4]; const float* ab[4];
    for (int i = 0; i < 4; ++i) {   // setup_inputs dict order: conv_w, conv_b, att_w, att_b per branch
        cw[i] = (const float*)d_in[2 + 4 * i];
        cb[i] = (const float*)d_in[3 + 4 * i];
        aw[i] = (const float*)d_in[4 + 4 * i];
        ab[i] = (const float*)d_in[5 + 4 * i];
    }
    const float* projw = (const float*)d_in[18];
    const float* projb = (const float*)d_in[19];
    const float* gm    = (const float*)d_in[20];
    const float* bt    = (const float*)d_in[21];
    float* ws  = (float*)d_ws;
    float* out = (float*)d_out;

    hipLaunchKernelGGL(precompute_tables, dim3(16), dim3(256), 0, stream,
                       emb,
                       cw[0], cb[0], aw[0], ab[0],
                       cw[1], cb[1], aw[1], ab[1],
                       cw[2], cb[2], aw[2], ab[2],
                       cw[3], cb[3], aw[3], ab[3],
                       ws);

    hipLaunchKernelGGL(fused_main, dim3(BATCH), dim3(256), 0, stream,
                       xidx, ws, projw, projb, gm, bt, out);
}

// Round 2
// 163.224 us; speedup vs baseline: 1.5645x; 1.5645x over previous
//
#include <hip/hip_runtime.h>
#include <math.h>

#define BATCH 4096
#define SEQL  512
#define NF    32
#define DEMB  8
#define DOUT  64

// window-table geometry: branches ks=2,3,4,5; window counts 25,125,625,3125
// swin concat offsets: 0,25,150,775 ; total 3900
// hwin (float offset in ws): 4096 + global_window_id*32
#define NWIN_TOTAL 3900
#define HWIN_OFF   4096

__device__ __forceinline__ float gelu_exact(float x) {
    return 0.5f * x * (1.0f + erff(x * 0.70710678118654752f));
}

// One thread per (global_window, filter): 3900*32 = 124800 work items.
// 32 consecutive lanes = one window; cross-lane reduce gives the attention score.
__global__ __launch_bounds__(256) void precompute_tables(
    const float* __restrict__ emb,
    const float* __restrict__ cw0, const float* __restrict__ cb0,
    const float* __restrict__ aw0, const float* __restrict__ ab0,
    const float* __restrict__ cw1, const float* __restrict__ cb1,
    const float* __restrict__ aw1, const float* __restrict__ ab1,
    const float* __restrict__ cw2, const float* __restrict__ cb2,
    const float* __restrict__ aw2, const float* __restrict__ ab2,
    const float* __restrict__ cw3, const float* __restrict__ cb3,
    const float* __restrict__ aw3, const float* __restrict__ ab3,
    float* __restrict__ ws)
{
    const int gid = blockIdx.x * blockDim.x + threadIdx.x;
    if (gid >= NWIN_TOTAL * NF) return;
    const int wgid = gid >> 5;      // global window id 0..3899
    const int f    = gid & 31;      // filter 0..31

    int w, ks;
    const float *cw, *cb, *aw, *ab;
    if (wgid < 25)       { w = wgid;       ks = 2; cw = cw0; cb = cb0; aw = aw0; ab = ab0; }
    else if (wgid < 150) { w = wgid - 25;  ks = 3; cw = cw1; cb = cb1; aw = aw1; ab = ab1; }
    else if (wgid < 775) { w = wgid - 150; ks = 4; cw = cw2; cb = cb2; aw = aw2; ab = ab2; }
    else                 { w = wgid - 775; ks = 5; cw = cw3; cb = cb3; aw = aw3; ab = ab3; }

    float h = cb[f];
    int ww = w;
    for (int t = ks - 1; t >= 0; --t) {     // tap t carries weight 5^(ks-1-t)
        int d = ww % 5; ww /= 5;
        const float* e = emb + d * DEMB;    // PAD row is zero in the input
#pragma unroll
        for (int c = 0; c < DEMB; ++c)
            h += e[c] * cw[(f * DEMB + c) * ks + t];
    }
    float g = gelu_exact(h);
    ws[HWIN_OFF + wgid * NF + f] = g;       // coalesced table write

    // attention score: reduce g*aw[f] over the 32 lanes of this window
    float s = g * aw[f];
#pragma unroll
    for (int off = 16; off; off >>= 1) s += __shfl_xor(s, off, 32);
    if (f == 0) ws[wgid] = s + ab[0];
}

__global__ __launch_bounds__(256) void fused_main(
    const int*   __restrict__ xidx,
    const float* __restrict__ ws,
    const float* __restrict__ projw, const float* __restrict__ projb,
    const float* __restrict__ gamma, const float* __restrict__ beta,
    float* __restrict__ out)
{
    __shared__ int    xs[SEQL];        // tokens
    __shared__ float2 pw[4][SEQL];     // per-branch (weight, byte-offset-as-float)
    __shared__ float  feat[4 * NF];

    const int b   = blockIdx.x;
    const int tid = threadIdx.x;

#pragma unroll
    for (int i = tid; i < SEQL / 4; i += 256)
        ((int4*)xs)[i] = ((const int4*)(xidx + b * SEQL))[i];
    __syncthreads();

    const int wave = tid >> 6;
    const int lane = tid & 63;

    constexpr int KS[4]  = {2, 3, 4, 5};
    constexpr int LP[4]  = {511, 510, 509, 508};
    constexpr int SWB[4] = {0, 25, 150, 775};

    const int ks = KS[wave];
    const int Lp = LP[wave];
    const float* swin = ws + SWB[wave];
    const float* hwin = ws + HWIN_OFF + SWB[wave] * NF;

    // ---- pass 1: window ids + scores, wave softmax ----
    float sv[8];
    float m = -INFINITY;
#pragma unroll
    for (int it = 0; it < 8; ++it) {
        int l = lane + it * 64;
        int w = 0; float s = -INFINITY;
        if (l < Lp) {
            w = xs[l];
            for (int t = 1; t < ks; ++t) w = w * 5 + xs[l + t];
            s = swin[w];
        }
        pw[wave][l].y = __int_as_float(w * (NF * 4));   // byte offset of row
        sv[it] = s;
        m = fmaxf(m, s);
    }
#pragma unroll
    for (int off = 32; off; off >>= 1) m = fmaxf(m, __shfl_xor(m, off));

    float ssum = 0.0f;
#pragma unroll
    for (int it = 0; it < 8; ++it) {
        int l = lane + it * 64;
        float e = __expf(sv[it] - m);   // exp(-inf)=0 for padded slots
        pw[wave][l].x = e;
        ssum += e;
    }
#pragma unroll
    for (int off = 32; off; off >>= 1) ssum += __shfl_xor(ssum, off);
    const float inv = 1.0f / ssum;

    // ---- pass 2: coalesced weighted pool ----
    // lane = posgrp*8 + quad : 8 consecutive lanes read the 8 float4s of ONE row
    const int quad = lane & 7;
    const int pg   = lane >> 3;

    float a0 = 0.f, a1 = 0.f, a2 = 0.f, a3 = 0.f;
#pragma unroll 16
    for (int it = 0; it < 64; ++it) {
        const int pos = it * 8 + pg;
        float2 t = pw[wave][pos];                       // broadcast ds_read_b64
        const float p = t.x;
        const char* rowp = (const char*)hwin + __float_as_int(t.y);
        float4 r = *(const float4*)(rowp + quad * 16);  // coalesced
        a0 += p * r.x; a1 += p * r.y; a2 += p * r.z; a3 += p * r.w;
    }

#pragma unroll
    for (int off = 8; off < 64; off <<= 1) {
        a0 += __shfl_xor(a0, off);
        a1 += __shfl_xor(a1, off);
        a2 += __shfl_xor(a2, off);
        a3 += __shfl_xor(a3, off);
    }
    if (lane < 8) {
        float* fp = feat + wave * NF + lane * 4;
        fp[0] = a0 * inv; fp[1] = a1 * inv; fp[2] = a2 * inv; fp[3] = a3 * inv;
    }
    __syncthreads();

    // ---- projection + GELU + LayerNorm (wave 0) ----
    if (tid < DOUT) {
        float z = projb[tid];
        const float4* pwr = (const float4*)(projw + tid * (4 * NF));
#pragma unroll
        for (int q = 0; q < 32; ++q) {
            float4 wq = pwr[q];
            const float* fj = feat + q * 4;
            z += wq.x * fj[0] + wq.y * fj[1] + wq.z * fj[2] + wq.w * fj[3];
        }
        z = gelu_exact(z);

        float s1 = z, s2 = z * z;
#pragma unroll
        for (int off = 32; off; off >>= 1) {
            s1 += __shfl_xor(s1, off);
            s2 += __shfl_xor(s2, off);
        }
        const float mu  = s1 * (1.0f / 64.0f);
        const float var = s2 * (1.0f / 64.0f) - mu * mu;
        const float r   = rsqrtf(var + 1e-5f);
        out[b * DOUT + tid] = (z - mu) * r * gamma[tid] + beta[tid];
    }
}

extern "C" void kernel_launch(void* const* d_in, const int* in_sizes, int n_in,
                              void* d_out, int out_size, void* d_ws, size_t ws_size,
                              hipStream_t stream) {
    const int*   xidx = (const int*)d_in[0];
    const float* emb  = (const float*)d_in[1];
    const float* cw[4]; const float* cb[4]; const float* aw[4]; const float* ab[4];
    for (int i = 0; i < 4; ++i) {
        cw[i] = (const float*)d_in[2 + 4 * i];
        cb[i] = (const float*)d_in[3 + 4 * i];
        aw[i] = (const float*)d_in[4 + 4 * i];
        ab[i] = (const float*)d_in[5 + 4 * i];
    }
    const float* projw = (const float*)d_in[18];
    const float* projb = (const float*)d_in[19];
    const float* gm    = (const float*)d_in[20];
    const float* bt    = (const float*)d_in[21];
    float* ws  = (float*)d_ws;
    float* out = (float*)d_out;

    hipLaunchKernelGGL(precompute_tables, dim3((NWIN_TOTAL * NF + 255) / 256), dim3(256), 0, stream,
                       emb,
                       cw[0], cb[0], aw[0], ab[0],
                       cw[1], cb[1], aw[1], ab[1],
                       cw[2], cb[2], aw[2], ab[2],
                       cw[3], cb[3], aw[3], ab[3],
                       ws);

    hipLaunchKernelGGL(fused_main, dim3(BATCH), dim3(256), 0, stream,
                       xidx, ws, projw, projb, gm, bt, out);
}